// Round 5
// baseline (444.598 us; speedup 1.0000x reference)
//
#include <hip/hip_runtime.h>

// Problem constants (from reference)
#define NNZ_TOT    2097152
#define N_CELLS    4096
#define N_PRE      30000
#define NUM_HID    128
#define CHUNK      128                  // nnz per wave
#define N_WAVES    (NNZ_TOT / CHUNK)    // 16384 waves

// ---------------------------------------------------------------------------
// Precompute 1: g_arr[i] = gidx[xc[i]]  (fuse first indirection)
// ---------------------------------------------------------------------------
__global__ __launch_bounds__(256) void fuse_gidx_kernel(
    const int* __restrict__ xc, const int* __restrict__ gidx,
    int* __restrict__ g_arr)
{
    const int i = blockIdx.x * blockDim.x + threadIdx.x;
    if (i < NNZ_TOT) g_arr[i] = gidx[xc[i]];
}

// ---------------------------------------------------------------------------
// Precompute 2: bf16 copy of the embedding table (rows 512 B -> 256 B).
// Halves gather volume AND lines-per-row; 7.7 MB nearly fits one XCD L2.
// ---------------------------------------------------------------------------
__device__ __forceinline__ unsigned short f2bf(float f) {
    union { float f; unsigned u; } c; c.f = f;
    unsigned u = c.u;
    u += 0x7fffu + ((u >> 16) & 1u);    // round-to-nearest-even
    return (unsigned short)(u >> 16);
}

__global__ __launch_bounds__(256) void convert_embs_kernel(
    const float* __restrict__ embs, unsigned short* __restrict__ ebf)
{
    const int i = blockIdx.x * blockDim.x + threadIdx.x;   // per 4 floats
    if (i * 4 < N_PRE * NUM_HID) {
        const float4 f = *reinterpret_cast<const float4*>(&embs[i * 4]);
        ushort4 o;
        o.x = f2bf(f.x); o.y = f2bf(f.y); o.z = f2bf(f.z); o.w = f2bf(f.w);
        *reinterpret_cast<ushort4*>(&ebf[i * 4]) = o;
    }
}

// ---------------------------------------------------------------------------
// Main kernel: one wave per 128-nnz chunk. Lane split: sub = lane&15 owns
// dims [sub*8, sub*8+8) (16 B bf16), quad = lane>>4 selects one of 4
// consecutive nnz -> ONE global_load_dwordx4 fetches 4 full embedding rows.
// Control data (rows/values/gene ids) via scalar loads + cndmask select.
// Rows sorted -> register accumulate; flush = shfl_xor(16/32) butterfly +
// quarter-wave atomicAdd (rare: ~1-2 per chunk).
// ---------------------------------------------------------------------------
__device__ __forceinline__ void fma_bf16x8(uint4 f, float vv, float acc[8]) {
    const unsigned uu[4] = { f.x, f.y, f.z, f.w };
    #pragma unroll
    for (int t = 0; t < 4; ++t) {
        const float lo = __uint_as_float(uu[t] << 16);
        const float hi = __uint_as_float(uu[t] & 0xffff0000u);
        acc[2 * t]     = fmaf(vv, lo, acc[2 * t]);
        acc[2 * t + 1] = fmaf(vv, hi, acc[2 * t + 1]);
    }
}

__device__ __forceinline__ void flush_acc(float* __restrict__ out, int row,
                                          int h8, int quad, float acc[8]) {
    #pragma unroll
    for (int k = 0; k < 8; ++k) {
        acc[k] += __shfl_xor(acc[k], 16);
        acc[k] += __shfl_xor(acc[k], 32);
    }
    if (quad == 0) {
        float* o = &out[(long)row * NUM_HID + h8];
        #pragma unroll
        for (int k = 0; k < 8; ++k) atomicAdd(o + k, acc[k]);
    }
    #pragma unroll
    for (int k = 0; k < 8; ++k) acc[k] = 0.f;
}

__global__ __launch_bounds__(256, 8) void omics_bf16_kernel(
    const float*          __restrict__ xv,    // [NNZ] values
    const int*            __restrict__ xr,    // [NNZ] rows (sorted)
    const int*            __restrict__ g_arr, // [NNZ] fused gene ids
    const unsigned short* __restrict__ ebf,   // [N_PRE,128] bf16
    float*                __restrict__ out)   // [N_CELLS,128]
{
    const int wave = (blockIdx.x * blockDim.x + threadIdx.x) >> 6;
    const int lane = threadIdx.x & 63;
    const int sub  = lane & 15;
    const int quad = lane >> 4;
    const int base = __builtin_amdgcn_readfirstlane(wave * CHUNK);
    const int h8   = sub * 8;

    float acc[8] = {0.f, 0.f, 0.f, 0.f, 0.f, 0.f, 0.f, 0.f};

    const int rF = xr[base];
    const int rL = xr[base + CHUNK - 1];

    if (rF == rL) {
        // ---- fast path: whole chunk in one row (~75% of chunks) ----
        for (int it = 0; it < CHUNK; it += 16) {
            int g[16]; float v[16];
            #pragma unroll
            for (int j = 0; j < 16; ++j) {           // uniform -> s_load
                g[j] = g_arr[base + it + j];
                v[j] = xv[base + it + j];
            }
            uint4 f[4];
            #pragma unroll
            for (int u = 0; u < 4; ++u) {
                int gg = g[4 * u];
                gg = (quad == 1) ? g[4 * u + 1] : gg;
                gg = (quad == 2) ? g[4 * u + 2] : gg;
                gg = (quad == 3) ? g[4 * u + 3] : gg;
                f[u] = *reinterpret_cast<const uint4*>(
                    &ebf[(long)gg * NUM_HID + h8]);
            }
            #pragma unroll
            for (int u = 0; u < 4; ++u) {
                float vv = v[4 * u];
                vv = (quad == 1) ? v[4 * u + 1] : vv;
                vv = (quad == 2) ? v[4 * u + 2] : vv;
                vv = (quad == 3) ? v[4 * u + 3] : vv;
                fma_bf16x8(f[u], vv, acc);
            }
        }
        flush_acc(out, rF, h8, quad, acc);
    } else {
        // ---- slow path: chunk crosses >=1 row boundary ----
        int cur = rF;
        for (int it = 0; it < CHUNK; it += 16) {
            const int i0 = base + it;
            const int rA = xr[i0];
            const int rB = xr[i0 + 15];
            if (rA == rB) {
                if (rA != cur) { flush_acc(out, cur, h8, quad, acc); cur = rA; }
                int g[16]; float v[16];
                #pragma unroll
                for (int j = 0; j < 16; ++j) {
                    g[j] = g_arr[i0 + j];
                    v[j] = xv[i0 + j];
                }
                uint4 f[4];
                #pragma unroll
                for (int u = 0; u < 4; ++u) {
                    int gg = g[4 * u];
                    gg = (quad == 1) ? g[4 * u + 1] : gg;
                    gg = (quad == 2) ? g[4 * u + 2] : gg;
                    gg = (quad == 3) ? g[4 * u + 3] : gg;
                    f[u] = *reinterpret_cast<const uint4*>(
                        &ebf[(long)gg * NUM_HID + h8]);
                }
                #pragma unroll
                for (int u = 0; u < 4; ++u) {
                    float vv = v[4 * u];
                    vv = (quad == 1) ? v[4 * u + 1] : vv;
                    vv = (quad == 2) ? v[4 * u + 2] : vv;
                    vv = (quad == 3) ? v[4 * u + 3] : vv;
                    fma_bf16x8(f[u], vv, acc);
                }
            } else {
                // element-wise: quad 0 processes alone (rare)
                #pragma unroll 4
                for (int j = 0; j < 16; ++j) {
                    const int r = xr[i0 + j];                 // uniform
                    if (r != cur) { flush_acc(out, cur, h8, quad, acc); cur = r; }
                    const int   gg = g_arr[i0 + j];           // uniform
                    const float vv = xv[i0 + j];              // uniform
                    if (quad == 0) {
                        const uint4 f = *reinterpret_cast<const uint4*>(
                            &ebf[(long)gg * NUM_HID + h8]);
                        fma_bf16x8(f, vv, acc);
                    }
                }
            }
        }
        flush_acc(out, cur, h8, quad, acc);
    }
}

// ---------------------------------------------------------------------------
// Fallback (ws too small for bf16 table): R4 fp32 paired-chunk kernel.
// ---------------------------------------------------------------------------
__device__ __forceinline__ void flush_row2(float* __restrict__ out, int row,
                                           int h, float2 acc) {
    float* o = &out[(long)row * NUM_HID + h];
    atomicAdd(o + 0, acc.x);
    atomicAdd(o + 1, acc.y);
}

template <bool PRE>
__global__ __launch_bounds__(256) void omics_fp32_kernel(
    const float* __restrict__ xv, const int* __restrict__ xr,
    const int* __restrict__ xc, const int* __restrict__ gidx,
    const int* __restrict__ g_arr, const float* __restrict__ embs,
    float* __restrict__ out)
{
    const int wave = (blockIdx.x * blockDim.x + threadIdx.x) >> 6;
    const int lane = threadIdx.x & 63;
    const int base = __builtin_amdgcn_readfirstlane(wave * CHUNK);
    const int h    = lane * 2;

    float2 acc = make_float2(0.f, 0.f);
    int cur = xr[base];
    for (int it = 0; it < CHUNK; it += 8) {
        const int i0 = base + it;
        #pragma unroll
        for (int j = 0; j < 8; ++j) {
            const int r = xr[i0 + j];
            if (r != cur) { flush_row2(out, cur, h, acc);
                            cur = r; acc = make_float2(0.f, 0.f); }
            const int   gg = PRE ? g_arr[i0 + j] : gidx[xc[i0 + j]];
            const float vv = xv[i0 + j];
            const float2 ff = *reinterpret_cast<const float2*>(
                &embs[(long)gg * NUM_HID + h]);
            acc.x = fmaf(vv, ff.x, acc.x);
            acc.y = fmaf(vv, ff.y, acc.y);
        }
    }
    flush_row2(out, cur, h, acc);
}

extern "C" void kernel_launch(void* const* d_in, const int* in_sizes, int n_in,
                              void* d_out, int out_size, void* d_ws, size_t ws_size,
                              hipStream_t stream) {
    const float* xv   = (const float*)d_in[0];
    const int*   xr   = (const int*)  d_in[1];
    const int*   xc   = (const int*)  d_in[2];
    const int*   gidx = (const int*)  d_in[3];
    const float* embs = (const float*)d_in[4];
    float*       out  = (float*)d_out;

    // Atomically accumulated -> zero first (harness poisons with 0xAA).
    hipMemsetAsync(out, 0, (size_t)out_size * sizeof(float), stream);

    const size_t g_bytes  = (size_t)NNZ_TOT * sizeof(int);          // 8 MB
    const size_t e_bytes  = (size_t)N_PRE * NUM_HID * 2;            // 7.7 MB
    const int    blocks   = (N_WAVES * 64) / 256;                   // 4096

    if (ws_size >= g_bytes + e_bytes) {
        int*            g_arr = (int*)d_ws;
        unsigned short* ebf   = (unsigned short*)((char*)d_ws + g_bytes);
        fuse_gidx_kernel<<<(NNZ_TOT + 255) / 256, 256, 0, stream>>>(
            xc, gidx, g_arr);
        convert_embs_kernel<<<(N_PRE * NUM_HID / 4 + 255) / 256, 256, 0, stream>>>(
            embs, ebf);
        omics_bf16_kernel<<<blocks, 256, 0, stream>>>(
            xv, xr, g_arr, ebf, out);
    } else if (ws_size >= g_bytes) {
        int* g_arr = (int*)d_ws;
        fuse_gidx_kernel<<<(NNZ_TOT + 255) / 256, 256, 0, stream>>>(
            xc, gidx, g_arr);
        omics_fp32_kernel<true><<<blocks, 256, 0, stream>>>(
            xv, xr, xc, gidx, g_arr, embs, out);
    } else {
        omics_fp32_kernel<false><<<blocks, 256, 0, stream>>>(
            xv, xr, xc, gidx, (const int*)nullptr, embs, out);
    }
}